// Round 13
// baseline (352.715 us; speedup 1.0000x reference)
//
#include <hip/hip_runtime.h>
#include <math.h>

#define NPTS   8192
#define BATCH  4
#define KNN    20
#define NKTOT  (NPTS*KNN)        // 163840 spatial positions per batch
#define EPS    1e-5f
#define TILE4  2048              // knn point tile (SoA, 32KB)
#define QCAP   40                // per-query candidate queue capacity (7-sigma)

typedef float v2f __attribute__((ext_vector_type(2)));

__device__ __forceinline__ float elu(float x) { return x > 0.0f ? x : expm1f(x); }
__device__ __forceinline__ float eluf(float x) { return x > 0.0f ? x : __expf(x) - 1.0f; }
__device__ __forceinline__ v2f splat2(float x) { v2f v; v.x = x; v.y = x; return v; }
__device__ __forceinline__ float rfl(float x) {
    return __uint_as_float(__builtin_amdgcn_readfirstlane(__float_as_uint(x)));
}

// monotone float <-> unsigned encoding for atomic max/min on floats
__device__ __forceinline__ unsigned fenc(float f) {
    unsigned b = __float_as_uint(f);
    return b ^ ((unsigned)(((int)b) >> 31) | 0x80000000u);
}
__device__ __forceinline__ float fdec(unsigned u) {
    unsigned b = (u & 0x80000000u) ? (u ^ 0x80000000u) : ~u;
    return __uint_as_float(b);
}

// ---------------------------------------------------------------------------
// K0: pack points into (x,y,z,-0.5*|p|^2) so knn score s = q.p + w gives
// dist = |q|^2 - 2s (ordering by s is exactly ordering by dist).
// ---------------------------------------------------------------------------
__global__ __launch_bounds__(256) void prep_kernel(const float* __restrict__ points,
                                                   float4* __restrict__ pts4)
{
    const int t = blockIdx.x * 256 + threadIdx.x;     // 32768
    const int b = t >> 13, n = t & (NPTS - 1);
    const float* px = points + b * 3 * NPTS;
    float x = px[n], y = px[NPTS + n], z = px[2 * NPTS + n];
    pts4[t] = make_float4(x, y, z, -0.5f * (x * x + y * y + z * z));
}

// ---------------------------------------------------------------------------
// K1: exact KNN (R9 best-measured form, 101us — knn is plateaued; frozen).
// 512 threads = 8 waves sharing an SoA LDS tile, register-prefetched double
// buffering. Pass 1: packed per-lane max scan + bitonic -> rank-44 of lane
// maxima = provable lower bound on 20th-best score (gate). Pass 2: parallel
// queue append. Final: 64-lane bitonic descending per query, ties -> smaller
// idx (exact lax.top_k order). Output layout [b][k][n] (coalesced consumers).
// grid: 512 blocks (128/batch, 64 queries/block).
// ---------------------------------------------------------------------------
__global__ __launch_bounds__(512, 6) void knn_kernel(const float4* __restrict__ pts4,
                                                     int* __restrict__ idx_out)
{
    __shared__ float tx[TILE4], ty[TILE4], tz[TILE4], tw[TILE4];   // 32 KB SoA
    __shared__ unsigned long long queue[64][QCAP];                 // 20 KB
    __shared__ int qcnt[64];

    const int tid  = threadIdx.x;
    const int lane = tid & 63;
    const int wv   = tid >> 6;            // 0..7
    const int b    = blockIdx.x >> 7;     // 128 blocks per batch
    const int q0   = (blockIdx.x & 127) * 64 + wv * 8;
    const float4* pb = pts4 + b * NPTS;

    if (tid < 64) qcnt[tid] = 0;

    float qx[8], qy[8], qz[8];
    v2f smax2[8];
#pragma unroll
    for (int q = 0; q < 8; ++q) {
        float4 qp = pb[q0 + q];
        qx[q] = rfl(qp.x); qy[q] = rfl(qp.y); qz[q] = rfl(qp.z);
        smax2[q] = splat2(-INFINITY);
    }

    float4 pf[4];
#pragma unroll
    for (int r = 0; r < 4; ++r) pf[r] = pb[tid + r * 512];   // prefetch tile 0

    // ---- pass 1: per-lane max score, 2 candidates/iter (packed) ----
    for (int t = 0; t < NPTS / TILE4; ++t) {
        __syncthreads();                       // previous tile's readers done
#pragma unroll
        for (int r = 0; r < 4; ++r) {
            int i = tid + r * 512;
            tx[i] = pf[r].x; ty[i] = pf[r].y; tz[i] = pf[r].z; tw[i] = pf[r].w;
        }
        __syncthreads();
        if (t + 1 < NPTS / TILE4) {
#pragma unroll
            for (int r = 0; r < 4; ++r) pf[r] = pb[(t + 1) * TILE4 + tid + r * 512];
        }
#pragma unroll 2
        for (int s = 0; s < TILE4 / 128; ++s) {
            v2f px = *(const v2f*)&tx[s * 128 + 2 * lane];
            v2f py = *(const v2f*)&ty[s * 128 + 2 * lane];
            v2f pz = *(const v2f*)&tz[s * 128 + 2 * lane];
            v2f pw = *(const v2f*)&tw[s * 128 + 2 * lane];
#pragma unroll
            for (int q = 0; q < 8; ++q) {
                v2f sv = __builtin_elementwise_fma(splat2(qx[q]), px,
                         __builtin_elementwise_fma(splat2(qy[q]), py,
                         __builtin_elementwise_fma(splat2(qz[q]), pz, pw)));
                smax2[q] = __builtin_elementwise_max(smax2[q], sv);
            }
        }
    }

#pragma unroll
    for (int r = 0; r < 4; ++r) pf[r] = pb[tid + r * 512];   // prefetch pass-2 tile 0

    // ---- bitonic sort lane maxima (ascending); rank-44 = 20th largest ----
    float sgate[8];
#pragma unroll
    for (int q = 0; q < 8; ++q) {
        float v = fmaxf(smax2[q].x, smax2[q].y);
#pragma unroll
        for (int k = 2; k <= 64; k <<= 1)
#pragma unroll
            for (int j = k >> 1; j >= 1; j >>= 1) {
                float o = __shfl_xor(v, j);
                bool up = ((lane & k) == 0);
                bool keepmin = (((lane & j) == 0) == up);
                v = keepmin ? fminf(v, o) : fmaxf(v, o);
            }
        float m = __shfl(v, 44);                      // lower bound on true 20th-best s
        sgate[q] = m - 1e-4f - 1e-5f * fabsf(m);      // margin vs fp recompute jitter
    }

    // ---- pass 2: gated parallel queue append (no serial chains) ----
    for (int t = 0; t < NPTS / TILE4; ++t) {
        __syncthreads();
#pragma unroll
        for (int r = 0; r < 4; ++r) {
            int i = tid + r * 512;
            tx[i] = pf[r].x; ty[i] = pf[r].y; tz[i] = pf[r].z; tw[i] = pf[r].w;
        }
        __syncthreads();
        if (t + 1 < NPTS / TILE4) {
#pragma unroll
            for (int r = 0; r < 4; ++r) pf[r] = pb[(t + 1) * TILE4 + tid + r * 512];
        }
        for (int s = 0; s < TILE4 / 128; ++s) {
            v2f px = *(const v2f*)&tx[s * 128 + 2 * lane];
            v2f py = *(const v2f*)&ty[s * 128 + 2 * lane];
            v2f pz = *(const v2f*)&tz[s * 128 + 2 * lane];
            v2f pw = *(const v2f*)&tw[s * 128 + 2 * lane];
            const int jb = t * TILE4 + s * 128 + 2 * lane;
#pragma unroll
            for (int q = 0; q < 8; ++q) {
                v2f sv = __builtin_elementwise_fma(splat2(qx[q]), px,
                         __builtin_elementwise_fma(splat2(qy[q]), py,
                         __builtin_elementwise_fma(splat2(qz[q]), pz, pw)));
                if (fmaxf(sv.x, sv.y) >= sgate[q]) {   // common case: skip both
#pragma unroll
                    for (int h = 0; h < 2; ++h) {
                        float svh = h ? sv.y : sv.x;
                        if (svh >= sgate[q]) {
                            int slot = atomicAdd(&qcnt[wv * 8 + q], 1);
                            if (slot < QCAP) {
                                unsigned long long key =
                                    ((unsigned long long)fenc(svh) << 32)
                                    | (unsigned)(NPTS - 1 - (jb + h));
                                queue[wv * 8 + q][slot] = key;
                            }
                        }
                    }
                }
            }
        }
    }
    __syncthreads();

    // ---- final: per query, 64-lane bitonic sort descending, emit top-20 ----
#pragma unroll
    for (int q = 0; q < 8; ++q) {
        int cq = qcnt[wv * 8 + q]; cq = cq < QCAP ? cq : QCAP;
        unsigned long long key = (lane < cq) ? queue[wv * 8 + q][lane] : 0ull;
#pragma unroll
        for (int k = 2; k <= 64; k <<= 1)
#pragma unroll
            for (int j = k >> 1; j >= 1; j >>= 1) {
                unsigned long long o = __shfl_xor(key, j);
                bool up = ((lane & k) == 0);
                bool keepmax = (((lane & j) == 0) == up);
                bool omax = o > key;
                key = (keepmax == omax) ? o : key;
            }
        if (lane < KNN)
            idx_out[(b * KNN + lane) * NPTS + (q0 + q)] =     // [b][k][n] layout
                NPTS - 1 - (int)(unsigned)(key & 0xFFFFFFFFu);
    }
}

// ---------------------------------------------------------------------------
// K2: x0 moments (6 sums + 21 upper-tri products). Each thread accumulates
// 8 elements (amortizes the 27x6 shuffle tree 8x); neighbor gather is ONE
// cache line via pts4[j] (was 3 scattered lines from the planar layout).
// grid: 320 blocks x 256 threads (80 blocks/batch, 2048 elems/block).
// ---------------------------------------------------------------------------
__global__ __launch_bounds__(256) void moments_x_kernel(const float4* __restrict__ pts4,
                                                        const int* __restrict__ idx,
                                                        float* __restrict__ sums1p)
{
    const int b  = blockIdx.x / 80;
    const int r0 = (blockIdx.x - b * 80) * 2048;
    const float4* pb = pts4 + b * NPTS;
    const int* ib = idx + b * NKTOT;

    float v[27];
#pragma unroll
    for (int i = 0; i < 27; ++i) v[i] = 0.f;

    for (int e = 0; e < 8; ++e) {
        const int id = r0 + e * 256 + threadIdx.x;   // [k][n] linear, coalesced
        const int n = id & (NPTS - 1);
        const int j = ib[id];
        float4 c4 = pb[n];
        float4 e4 = pb[j];
        float x[6] = { c4.x, c4.y, c4.z, e4.x - c4.x, e4.y - c4.y, e4.z - c4.z };
        int p = 6;
#pragma unroll
        for (int d = 0; d < 6; ++d) {
            v[d] += x[d];
#pragma unroll
            for (int ee = d; ee < 6; ++ee) v[p++] += x[d] * x[ee];
        }
    }
#pragma unroll
    for (int i = 0; i < 27; ++i)
        for (int o = 32; o > 0; o >>= 1) v[i] += __shfl_xor(v[i], o);

    __shared__ float red[4][27];
    const int lane = threadIdx.x & 63, w = threadIdx.x >> 6;
    if (lane == 0)
#pragma unroll
        for (int i = 0; i < 27; ++i) red[w][i] = v[i];
    __syncthreads();
    if (threadIdx.x < 27) {
        float acc = red[0][threadIdx.x] + red[1][threadIdx.x] + red[2][threadIdx.x] + red[3][threadIdx.x];
        int slot = blockIdx.x & 63;
        atomicAdd(&sums1p[(slot * BATCH + b) * 27 + threadIdx.x], acc);
    }
}

// ---------------------------------------------------------------------------
// K3: finalize GN1 stats -> folded per-channel weights w1f[b][c][8]:
// slots 0..5 = s*W1[c][:], slot 6 = t, slot 7 = 0.  1 block x 128 threads.
// ---------------------------------------------------------------------------
__global__ void finalize1_kernel(const float* __restrict__ sums1p,
                                 const float* __restrict__ w1, const float* __restrict__ b1,
                                 const float* __restrict__ g1, const float* __restrict__ beta1,
                                 float* __restrict__ w1f)
{
    __shared__ float S[BATCH][27];
    const int t = threadIdx.x;
    if (t < 108) {
        int b = t / 27, i = t % 27;
        float acc = 0.f;
        for (int s = 0; s < 64; ++s) acc += sums1p[(s * BATCH + b) * 27 + i];
        S[b][i] = acc;
    }
    __syncthreads();
    const int b = t >> 5, c = t & 31;
    const float invS = 1.0f / (float)NKTOT;
    float Ex[6], M[6][6];
#pragma unroll
    for (int d = 0; d < 6; ++d) Ex[d] = S[b][d] * invS;
    int p = 6;
#pragma unroll
    for (int d = 0; d < 6; ++d)
#pragma unroll
        for (int e = d; e < 6; ++e) { float v = S[b][p++] * invS; M[d][e] = v; M[e][d] = v; }
    const int g = c >> 2;
    float msum = 0.f, qsum = 0.f;
    for (int cc = g * 4; cc < g * 4 + 4; ++cc) {
        float w[6];
#pragma unroll
        for (int d = 0; d < 6; ++d) w[d] = w1[cc * 6 + d];
        float dotEx = 0.f;
#pragma unroll
        for (int d = 0; d < 6; ++d) dotEx += w[d] * Ex[d];
        float Ey = dotEx + b1[cc];
        float Ey2 = 0.f;
#pragma unroll
        for (int d = 0; d < 6; ++d)
#pragma unroll
            for (int e = 0; e < 6; ++e) Ey2 += w[d] * w[e] * M[d][e];
        Ey2 += 2.0f * b1[cc] * dotEx + b1[cc] * b1[cc];
        msum += Ey; qsum += Ey2;
    }
    float m = msum * 0.25f;
    float var = qsum * 0.25f - m * m;
    float inv = rsqrtf(var + EPS);
    float s = g1[c] * inv;
    float tt = s * (b1[c] - m) + beta1[c];
    float* o = w1f + (b * 32 + c) * 8;
#pragma unroll
    for (int d = 0; d < 6; ++d) o[d] = s * w1[c * 6 + d];
    o[6] = tt; o[7] = 0.f;
}

// ---------------------------------------------------------------------------
// K4: fused main pass (R12 form, coalesced idx via [b][k][n]).
// Block = (b, k, 512 n's) as 4 phases of 128 n. z1[32][128] in LDS,
// GEMM thread tile 4c x 8n, running stats in registers, one butterfly +
// 144 atomics per block. grid: 4*20*16 = 1280 blocks x 256 thr.
// ---------------------------------------------------------------------------
__global__ __launch_bounds__(256, 5) void fused_main_kernel(
    const float4* __restrict__ pts4, const int* __restrict__ idxb,
    const float* __restrict__ w1f, const float* __restrict__ w2, const float* __restrict__ b2,
    float* __restrict__ sums2p, unsigned int* __restrict__ maxenc, unsigned int* __restrict__ minenc)
{
    __shared__ __align__(16) float w2t[32 * 64];    // W2^T: [k][c]   8 KB
    __shared__ __align__(16) float z1s[32 * 128];   // z1:   [k][n]  16 KB
    __shared__ __align__(16) float4 w1s4[64];       // folded W1 [32][8]
    __shared__ float b2s[64];
    __shared__ float redmx[256], redmn[256], sqred[128];

    const int t   = threadIdx.x;
    const int blk = blockIdx.x;
    const int nc  = blk & 15;
    const int k   = (blk >> 4) % 20;
    const int b   = blk / 320;          // 320 blocks per batch (16 nc * 20 k)

    for (int i = t; i < 512; i += 256) {
        float4 v = ((const float4*)w2)[i];
        int c = i >> 3, kq = (i & 7) * 4;
        w2t[(kq + 0) * 64 + c] = v.x; w2t[(kq + 1) * 64 + c] = v.y;
        w2t[(kq + 2) * 64 + c] = v.z; w2t[(kq + 3) * 64 + c] = v.w;
    }
    if (t < 64) { w1s4[t] = ((const float4*)w1f)[b * 64 + t]; b2s[t] = b2[t]; }

    const int wvi  = t >> 6;
    const int nf   = t & 127;
    const int cgf  = t >> 7;
    const int cq   = t & 15;
    const int ng   = t >> 4;
    const int c0   = cq * 4;
    const int n0   = ng * 8;
    const float4* pb = pts4 + b * NPTS;
    const int nbase = nc * 512;
    const int* idxrow = idxb + (b * KNN + k) * NPTS;   // [b][k][n]: coalesced

    float mx[4], mn[4];
#pragma unroll
    for (int ci = 0; ci < 4; ++ci) { mx[ci] = -INFINITY; mn[ci] = INFINITY; }
    float gs = 0.f, gq = 0.f;

    for (int ph = 0; ph < 4; ++ph) {
        const int n = nbase + ph * 128 + nf;
        const int j = idxrow[n];
        float4 c4 = pb[n];
        float4 e4 = pb[j];
        float x0[6] = { c4.x, c4.y, c4.z, e4.x - c4.x, e4.y - c4.y, e4.z - c4.z };

        __syncthreads();
#pragma unroll
        for (int jj = 0; jj < 16; ++jj) {
            int c = cgf * 16 + jj;
            float4 wA = w1s4[c * 2 + 0];
            float4 wB = w1s4[c * 2 + 1];
            float z = wB.z;
            z = fmaf(wA.x, x0[0], z); z = fmaf(wA.y, x0[1], z); z = fmaf(wA.z, x0[2], z);
            z = fmaf(wA.w, x0[3], z); z = fmaf(wB.x, x0[4], z); z = fmaf(wB.y, x0[5], z);
            z1s[c * 128 + nf] = eluf(z);
        }
        __syncthreads();

        float acc[4][8];
#pragma unroll
        for (int ci = 0; ci < 4; ++ci) {
            float bb = b2s[c0 + ci];
#pragma unroll
            for (int pj = 0; pj < 8; ++pj) acc[ci][pj] = bb;
        }
#pragma unroll
        for (int kk = 0; kk < 32; ++kk) {
            float4 av = *(const float4*)&w2t[kk * 64 + c0];
            float4 z0 = *(const float4*)&z1s[kk * 128 + n0];
            float4 z1v = *(const float4*)&z1s[kk * 128 + n0 + 4];
            float avv[4] = { av.x, av.y, av.z, av.w };
            float zvv[8] = { z0.x, z0.y, z0.z, z0.w, z1v.x, z1v.y, z1v.z, z1v.w };
#pragma unroll
            for (int ci = 0; ci < 4; ++ci)
#pragma unroll
                for (int pj = 0; pj < 8; ++pj) acc[ci][pj] = fmaf(avv[ci], zvv[pj], acc[ci][pj]);
        }
#pragma unroll
        for (int ci = 0; ci < 4; ++ci)
#pragma unroll
            for (int pj = 0; pj < 8; ++pj) {
                float v = acc[ci][pj];
                gs += v; gq = fmaf(v, v, gq);
                mx[ci] = fmaxf(mx[ci], v); mn[ci] = fminf(mn[ci], v);
            }
    }

#pragma unroll
    for (int m = 16; m <= 32; m <<= 1) {
#pragma unroll
        for (int ci = 0; ci < 4; ++ci) {
            mx[ci] = fmaxf(mx[ci], __shfl_xor(mx[ci], m));
            mn[ci] = fminf(mn[ci], __shfl_xor(mn[ci], m));
        }
        gs += __shfl_xor(gs, m);
        gq += __shfl_xor(gq, m);
    }
    if ((t & 63) < 16) {
#pragma unroll
        for (int ci = 0; ci < 4; ++ci) {
            redmx[wvi * 64 + cq * 4 + ci] = mx[ci];
            redmn[wvi * 64 + cq * 4 + ci] = mn[ci];
        }
        sqred[(wvi * 16 + cq) * 2 + 0] = gs;
        sqred[(wvi * 16 + cq) * 2 + 1] = gq;
    }
    __syncthreads();
    if (t < 64) {
        float m = fmaxf(fmaxf(redmx[t], redmx[64 + t]), fmaxf(redmx[128 + t], redmx[192 + t]));
        atomicMax(&maxenc[(b * 64 + t) * KNN + k], fenc(m));
    } else if (t < 128) {
        int c = t - 64;
        float m = fminf(fminf(redmn[c], redmn[64 + c]), fminf(redmn[128 + c], redmn[192 + c]));
        atomicMin(&minenc[(b * 64 + c) * KNN + k], fenc(m));
    } else if (t < 144) {
        int i2 = t - 128, g = i2 >> 1, w = i2 & 1;
        float v = 0.f;
#pragma unroll
        for (int wv2 = 0; wv2 < 4; ++wv2)
            v += sqred[(wv2 * 16 + 2 * g) * 2 + w] + sqred[(wv2 * 16 + 2 * g + 1) * 2 + w];
        int slot = blk & 63;
        atomicAdd(&sums2p[((slot * BATCH + b) * 8 + g) * 2 + w], v);
    }
}

// ---------------------------------------------------------------------------
// K5: fused tail: build m1 (GN2 of branch-1) -> conv 64->512 + GN + ELU ->
// conv 512->1024 + GN + ELU -> out. Block = (b, GN-B group g of 128 ch);
// each block redundantly computes the full y_a[512][20] for its b in LDS so
// ALL GroupNorm stats are block-local (zero cross-block comms, 1 launch
// replaces 5). grid: 32 blocks x 512 threads.
// ---------------------------------------------------------------------------
__global__ __launch_bounds__(512) void p2_fused_kernel(
    const float* __restrict__ sums2p,
    const unsigned int* __restrict__ maxenc, const unsigned int* __restrict__ minenc,
    const float* __restrict__ g1, const float* __restrict__ bt1,
    const float* __restrict__ wA, const float* __restrict__ bA,
    const float* __restrict__ gA, const float* __restrict__ btA,
    const float* __restrict__ wB, const float* __restrict__ bB,
    const float* __restrict__ gB, const float* __restrict__ btB,
    float* __restrict__ out)
{
    __shared__ float m1s[64 * 20];      // 5 KB
    __shared__ float ya[512 * 20];      // 40 KB
    __shared__ float statsl[16];
    __shared__ float m2mean[8], m2inv[8], meanA[8], invA[8], gnb[2];

    const int t = threadIdx.x;
    const int b = blockIdx.x >> 3;
    const int g = blockIdx.x & 7;       // GN-B group == output chunk of 128

    // --- branch-1 GN2 stats for this b (redundant per block, trivial) ---
    if (t < 16) {
        int gg = t >> 1, w = t & 1;
        float s = 0.f;
        for (int sl = 0; sl < 64; ++sl) s += sums2p[((sl * BATCH + b) * 8 + gg) * 2 + w];
        statsl[t] = s;
    }
    __syncthreads();
    if (t < 8) {
        const float cnt = 8.0f * (float)NKTOT;
        float m = statsl[t * 2 + 0] / cnt;
        float var = statsl[t * 2 + 1] / cnt - m * m;
        m2mean[t] = m; m2inv[t] = rsqrtf(var + EPS);
    }
    __syncthreads();
    // --- m1[64][20] = ELU(GN2 applied to max-or-min over n) ---
    for (int i = t; i < 1280; i += 512) {
        int c = i / 20;
        int gg = c >> 3;
        float sc = g1[c] * m2inv[gg];
        float tt = bt1[c] - sc * m2mean[gg];
        float y = (sc >= 0.f) ? fdec(maxenc[b * 1280 + i]) : fdec(minenc[b * 1280 + i]);
        m1s[i] = elu(sc * y + tt);
    }
    __syncthreads();

    // --- GEMM-A: y_a[512][20] (full, redundant per block) ---
    float va[20];
#pragma unroll
    for (int r = 0; r < 20; ++r) {
        int oid = r * 512 + t;
        int o = oid / 20, k = oid - o * 20;
        float acc = bA[o];
        const float* wr = wA + o * 64;
#pragma unroll
        for (int c = 0; c < 64; c += 4) {
            float4 wv = *(const float4*)&wr[c];
            acc += wv.x * m1s[(c + 0) * 20 + k] + wv.y * m1s[(c + 1) * 20 + k]
                 + wv.z * m1s[(c + 2) * 20 + k] + wv.w * m1s[(c + 3) * 20 + k];
        }
        va[r] = acc;
        ya[o * 20 + k] = acc;
    }
    __syncthreads();

    // --- GN-A stats: 8 teams of 64 lanes, one group each (1280 vals) ---
    {
        int team = t >> 6, lane = t & 63;
        float s = 0.f, q = 0.f;
        for (int i = lane; i < 1280; i += 64) {
            float v = ya[team * 1280 + i];
            s += v; q = fmaf(v, v, q);
        }
#pragma unroll
        for (int m = 1; m <= 32; m <<= 1) { s += __shfl_xor(s, m); q += __shfl_xor(q, m); }
        if (lane == 0) {
            float mm = s / 1280.0f;
            float var = q / 1280.0f - mm * mm;
            meanA[team] = mm; invA[team] = rsqrtf(var + EPS);
        }
    }
    __syncthreads();
    // --- apply GN-A + ELU into ya ---
#pragma unroll
    for (int r = 0; r < 20; ++r) {
        int oid = r * 512 + t;
        int o = oid / 20, k = oid - o * 20;
        int gg = o >> 6;
        ya[o * 20 + k] = elu(gA[o] * invA[gg] * (va[r] - meanA[gg]) + btA[o]);
    }
    __syncthreads();

    // --- GEMM-B: this block's 128 channels x 20 k ---
    float vb[5];
#pragma unroll
    for (int r = 0; r < 5; ++r) {
        int oid = r * 512 + t;
        int ol = oid / 20, k = oid - ol * 20;
        int o = g * 128 + ol;
        float acc = bB[o];
        const float* wr = wB + o * 512;
#pragma unroll 8
        for (int c = 0; c < 512; c += 4) {
            float4 wv = *(const float4*)&wr[c];
            acc += wv.x * ya[(c + 0) * 20 + k] + wv.y * ya[(c + 1) * 20 + k]
                 + wv.z * ya[(c + 2) * 20 + k] + wv.w * ya[(c + 3) * 20 + k];
        }
        vb[r] = acc;
    }
    // --- GN-B stats: whole block is one group (2560 vals) ---
    {
        float s = 0.f, q = 0.f;
#pragma unroll
        for (int r = 0; r < 5; ++r) { s += vb[r]; q = fmaf(vb[r], vb[r], q); }
#pragma unroll
        for (int m = 1; m <= 32; m <<= 1) { s += __shfl_xor(s, m); q += __shfl_xor(q, m); }
        int wvid = t >> 6, lane = t & 63;
        if (lane == 0) { statsl[wvid * 2] = s; statsl[wvid * 2 + 1] = q; }
    }
    __syncthreads();
    if (t == 0) {
        float s = 0.f, q = 0.f;
        for (int w = 0; w < 8; ++w) { s += statsl[w * 2]; q += statsl[w * 2 + 1]; }
        float mm = s / 2560.0f;
        float var = q / 2560.0f - mm * mm;
        gnb[0] = mm; gnb[1] = rsqrtf(var + EPS);
    }
    __syncthreads();
    const float mB = gnb[0], iB = gnb[1];
#pragma unroll
    for (int r = 0; r < 5; ++r) {
        int oid = r * 512 + t;
        int ol = oid / 20, k = oid - ol * 20;
        int o = g * 128 + ol;
        out[b * 20480 + o * 20 + k] = elu(gB[o] * iB * (vb[r] - mB) + btB[o]);
    }
}

// ---------------------------------------------------------------------------
extern "C" void kernel_launch(void* const* d_in, const int* in_sizes, int n_in,
                              void* d_out, int out_size, void* d_ws, size_t ws_size,
                              hipStream_t stream)
{
    const float* points  = (const float*)d_in[0];
    const float* p1_w0   = (const float*)d_in[1];
    const float* p1_b0   = (const float*)d_in[2];
    const float* p1_g0   = (const float*)d_in[3];
    const float* p1_bt0  = (const float*)d_in[4];
    const float* p1_w1   = (const float*)d_in[5];
    const float* p1_b1   = (const float*)d_in[6];
    const float* p1_g1   = (const float*)d_in[7];
    const float* p1_bt1  = (const float*)d_in[8];
    const float* p2_w0   = (const float*)d_in[9];
    const float* p2_b0   = (const float*)d_in[10];
    const float* p2_g0   = (const float*)d_in[11];
    const float* p2_bt0  = (const float*)d_in[12];
    const float* p2_w1   = (const float*)d_in[13];
    const float* p2_b1   = (const float*)d_in[14];
    const float* p2_g1   = (const float*)d_in[15];
    const float* p2_bt1  = (const float*)d_in[16];
    float* out = (float*)d_out;

    float* ws = (float*)d_ws;
    int*      idx     = (int*)ws;                    // 655360  ([b][k][n])
    float*    sums1p  = ws + 655360;                 // 6912   (zero)
    float*    sums2p  = sums1p + 6912;               // 4096   (zero)
    float*    pad0    = sums2p + 4096;               // 2048   (unused, keeps offsets)
    unsigned* maxenc  = (unsigned*)(pad0 + 2048);    // 5120   (zero)
    unsigned* minenc  = maxenc + 5120;               // 5120   (0xFF)
    float*    w1f     = (float*)(minenc + 5120);     // 1024
    float*    pts4f   = w1f + 1024;                  // 131072 (32768 float4)
    float4*   pts4    = (float4*)pts4f;

    hipMemsetAsync(sums1p, 0, (6912 + 4096 + 2048 + 5120) * sizeof(float), stream);
    hipMemsetAsync(minenc, 0xFF, 5120 * sizeof(unsigned), stream);

    prep_kernel<<<128, 256, 0, stream>>>(points, pts4);
    knn_kernel<<<512, 512, 0, stream>>>(pts4, idx);
    moments_x_kernel<<<320, 256, 0, stream>>>(pts4, idx, sums1p);
    finalize1_kernel<<<1, 128, 0, stream>>>(sums1p, p1_w0, p1_b0, p1_g0, p1_bt0, w1f);
    // grid MUST be 1280 = 4 b * 20 k * 16 nc  (b = blk/320; larger grids give
    // b >= BATCH -> OOB idx reads -> memory fault, see R4 crash)
    fused_main_kernel<<<1280, 256, 0, stream>>>(pts4, idx, w1f, p1_w1, p1_b1,
                                                sums2p, maxenc, minenc);
    p2_fused_kernel<<<32, 512, 0, stream>>>(sums2p, maxenc, minenc, p1_g1, p1_bt1,
                                            p2_w0, p2_b0, p2_g0, p2_bt0,
                                            p2_w1, p2_b1, p2_g1, p2_bt1, out);
}

// Round 14
// 272.826 us; speedup vs baseline: 1.2928x; 1.2928x over previous
//
#include <hip/hip_runtime.h>
#include <math.h>

#define NPTS   8192
#define BATCH  4
#define KNN    20
#define NKTOT  (NPTS*KNN)        // 163840 spatial positions per batch
#define EPS    1e-5f
#define TILE4  2048              // knn point tile (SoA, 32KB)
#define QCAP   40                // per-query candidate queue capacity (7-sigma)

typedef float v2f __attribute__((ext_vector_type(2)));

__device__ __forceinline__ float elu(float x) { return x > 0.0f ? x : expm1f(x); }
__device__ __forceinline__ float eluf(float x) { return x > 0.0f ? x : __expf(x) - 1.0f; }
__device__ __forceinline__ v2f splat2(float x) { v2f v; v.x = x; v.y = x; return v; }
__device__ __forceinline__ float rfl(float x) {
    return __uint_as_float(__builtin_amdgcn_readfirstlane(__float_as_uint(x)));
}

// monotone float <-> unsigned encoding for atomic max/min on floats
__device__ __forceinline__ unsigned fenc(float f) {
    unsigned b = __float_as_uint(f);
    return b ^ ((unsigned)(((int)b) >> 31) | 0x80000000u);
}
__device__ __forceinline__ float fdec(unsigned u) {
    unsigned b = (u & 0x80000000u) ? (u ^ 0x80000000u) : ~u;
    return __uint_as_float(b);
}

// ---------------------------------------------------------------------------
// K0: pack points into (x,y,z,-0.5*|p|^2) so knn score s = q.p + w gives
// dist = |q|^2 - 2s (ordering by s is exactly ordering by dist).
// ---------------------------------------------------------------------------
__global__ __launch_bounds__(256) void prep_kernel(const float* __restrict__ points,
                                                   float4* __restrict__ pts4)
{
    const int t = blockIdx.x * 256 + threadIdx.x;     // 32768
    const int b = t >> 13, n = t & (NPTS - 1);
    const float* px = points + b * 3 * NPTS;
    float x = px[n], y = px[NPTS + n], z = px[2 * NPTS + n];
    pts4[t] = make_float4(x, y, z, -0.5f * (x * x + y * y + z * z));
}

// ---------------------------------------------------------------------------
// K1: exact KNN (R9 best-measured form, 101us — knn is plateaued; frozen).
// 512 threads = 8 waves sharing an SoA LDS tile, register-prefetched double
// buffering. Pass 1: packed per-lane max scan + bitonic -> rank-44 of lane
// maxima = provable lower bound on 20th-best score (gate). Pass 2: parallel
// queue append. Final: 64-lane bitonic descending per query, ties -> smaller
// idx (exact lax.top_k order). Output layout [b][k][n] (coalesced consumers).
// grid: 512 blocks (128/batch, 64 queries/block).
// ---------------------------------------------------------------------------
__global__ __launch_bounds__(512, 6) void knn_kernel(const float4* __restrict__ pts4,
                                                     int* __restrict__ idx_out)
{
    __shared__ float tx[TILE4], ty[TILE4], tz[TILE4], tw[TILE4];   // 32 KB SoA
    __shared__ unsigned long long queue[64][QCAP];                 // 20 KB
    __shared__ int qcnt[64];

    const int tid  = threadIdx.x;
    const int lane = tid & 63;
    const int wv   = tid >> 6;            // 0..7
    const int b    = blockIdx.x >> 7;     // 128 blocks per batch
    const int q0   = (blockIdx.x & 127) * 64 + wv * 8;
    const float4* pb = pts4 + b * NPTS;

    if (tid < 64) qcnt[tid] = 0;

    float qx[8], qy[8], qz[8];
    v2f smax2[8];
#pragma unroll
    for (int q = 0; q < 8; ++q) {
        float4 qp = pb[q0 + q];
        qx[q] = rfl(qp.x); qy[q] = rfl(qp.y); qz[q] = rfl(qp.z);
        smax2[q] = splat2(-INFINITY);
    }

    float4 pf[4];
#pragma unroll
    for (int r = 0; r < 4; ++r) pf[r] = pb[tid + r * 512];   // prefetch tile 0

    // ---- pass 1: per-lane max score, 2 candidates/iter (packed) ----
    for (int t = 0; t < NPTS / TILE4; ++t) {
        __syncthreads();                       // previous tile's readers done
#pragma unroll
        for (int r = 0; r < 4; ++r) {
            int i = tid + r * 512;
            tx[i] = pf[r].x; ty[i] = pf[r].y; tz[i] = pf[r].z; tw[i] = pf[r].w;
        }
        __syncthreads();
        if (t + 1 < NPTS / TILE4) {
#pragma unroll
            for (int r = 0; r < 4; ++r) pf[r] = pb[(t + 1) * TILE4 + tid + r * 512];
        }
#pragma unroll 2
        for (int s = 0; s < TILE4 / 128; ++s) {
            v2f px = *(const v2f*)&tx[s * 128 + 2 * lane];
            v2f py = *(const v2f*)&ty[s * 128 + 2 * lane];
            v2f pz = *(const v2f*)&tz[s * 128 + 2 * lane];
            v2f pw = *(const v2f*)&tw[s * 128 + 2 * lane];
#pragma unroll
            for (int q = 0; q < 8; ++q) {
                v2f sv = __builtin_elementwise_fma(splat2(qx[q]), px,
                         __builtin_elementwise_fma(splat2(qy[q]), py,
                         __builtin_elementwise_fma(splat2(qz[q]), pz, pw)));
                smax2[q] = __builtin_elementwise_max(smax2[q], sv);
            }
        }
    }

#pragma unroll
    for (int r = 0; r < 4; ++r) pf[r] = pb[tid + r * 512];   // prefetch pass-2 tile 0

    // ---- bitonic sort lane maxima (ascending); rank-44 = 20th largest ----
    float sgate[8];
#pragma unroll
    for (int q = 0; q < 8; ++q) {
        float v = fmaxf(smax2[q].x, smax2[q].y);
#pragma unroll
        for (int k = 2; k <= 64; k <<= 1)
#pragma unroll
            for (int j = k >> 1; j >= 1; j >>= 1) {
                float o = __shfl_xor(v, j);
                bool up = ((lane & k) == 0);
                bool keepmin = (((lane & j) == 0) == up);
                v = keepmin ? fminf(v, o) : fmaxf(v, o);
            }
        float m = __shfl(v, 44);                      // lower bound on true 20th-best s
        sgate[q] = m - 1e-4f - 1e-5f * fabsf(m);      // margin vs fp recompute jitter
    }

    // ---- pass 2: gated parallel queue append (no serial chains) ----
    for (int t = 0; t < NPTS / TILE4; ++t) {
        __syncthreads();
#pragma unroll
        for (int r = 0; r < 4; ++r) {
            int i = tid + r * 512;
            tx[i] = pf[r].x; ty[i] = pf[r].y; tz[i] = pf[r].z; tw[i] = pf[r].w;
        }
        __syncthreads();
        if (t + 1 < NPTS / TILE4) {
#pragma unroll
            for (int r = 0; r < 4; ++r) pf[r] = pb[(t + 1) * TILE4 + tid + r * 512];
        }
        for (int s = 0; s < TILE4 / 128; ++s) {
            v2f px = *(const v2f*)&tx[s * 128 + 2 * lane];
            v2f py = *(const v2f*)&ty[s * 128 + 2 * lane];
            v2f pz = *(const v2f*)&tz[s * 128 + 2 * lane];
            v2f pw = *(const v2f*)&tw[s * 128 + 2 * lane];
            const int jb = t * TILE4 + s * 128 + 2 * lane;
#pragma unroll
            for (int q = 0; q < 8; ++q) {
                v2f sv = __builtin_elementwise_fma(splat2(qx[q]), px,
                         __builtin_elementwise_fma(splat2(qy[q]), py,
                         __builtin_elementwise_fma(splat2(qz[q]), pz, pw)));
                if (fmaxf(sv.x, sv.y) >= sgate[q]) {   // common case: skip both
#pragma unroll
                    for (int h = 0; h < 2; ++h) {
                        float svh = h ? sv.y : sv.x;
                        if (svh >= sgate[q]) {
                            int slot = atomicAdd(&qcnt[wv * 8 + q], 1);
                            if (slot < QCAP) {
                                unsigned long long key =
                                    ((unsigned long long)fenc(svh) << 32)
                                    | (unsigned)(NPTS - 1 - (jb + h));
                                queue[wv * 8 + q][slot] = key;
                            }
                        }
                    }
                }
            }
        }
    }
    __syncthreads();

    // ---- final: per query, 64-lane bitonic sort descending, emit top-20 ----
#pragma unroll
    for (int q = 0; q < 8; ++q) {
        int cq = qcnt[wv * 8 + q]; cq = cq < QCAP ? cq : QCAP;
        unsigned long long key = (lane < cq) ? queue[wv * 8 + q][lane] : 0ull;
#pragma unroll
        for (int k = 2; k <= 64; k <<= 1)
#pragma unroll
            for (int j = k >> 1; j >= 1; j >>= 1) {
                unsigned long long o = __shfl_xor(key, j);
                bool up = ((lane & k) == 0);
                bool keepmax = (((lane & j) == 0) == up);
                bool omax = o > key;
                key = (keepmax == omax) ? o : key;
            }
        if (lane < KNN)
            idx_out[(b * KNN + lane) * NPTS + (q0 + q)] =     // [b][k][n] layout
                NPTS - 1 - (int)(unsigned)(key & 0xFFFFFFFFu);
    }
}

// ---------------------------------------------------------------------------
// K2: x0 moments (6 sums + 21 upper-tri products). Each thread accumulates
// 8 elements; neighbor gather is ONE cache line via pts4[j].
// grid: 320 blocks x 256 threads (80 blocks/batch, 2048 elems/block).
// ---------------------------------------------------------------------------
__global__ __launch_bounds__(256) void moments_x_kernel(const float4* __restrict__ pts4,
                                                        const int* __restrict__ idx,
                                                        float* __restrict__ sums1p)
{
    const int b  = blockIdx.x / 80;
    const int r0 = (blockIdx.x - b * 80) * 2048;
    const float4* pb = pts4 + b * NPTS;
    const int* ib = idx + b * NKTOT;

    float v[27];
#pragma unroll
    for (int i = 0; i < 27; ++i) v[i] = 0.f;

    for (int e = 0; e < 8; ++e) {
        const int id = r0 + e * 256 + threadIdx.x;   // [k][n] linear, coalesced
        const int n = id & (NPTS - 1);
        const int j = ib[id];
        float4 c4 = pb[n];
        float4 e4 = pb[j];
        float x[6] = { c4.x, c4.y, c4.z, e4.x - c4.x, e4.y - c4.y, e4.z - c4.z };
        int p = 6;
#pragma unroll
        for (int d = 0; d < 6; ++d) {
            v[d] += x[d];
#pragma unroll
            for (int ee = d; ee < 6; ++ee) v[p++] += x[d] * x[ee];
        }
    }
#pragma unroll
    for (int i = 0; i < 27; ++i)
        for (int o = 32; o > 0; o >>= 1) v[i] += __shfl_xor(v[i], o);

    __shared__ float red[4][27];
    const int lane = threadIdx.x & 63, w = threadIdx.x >> 6;
    if (lane == 0)
#pragma unroll
        for (int i = 0; i < 27; ++i) red[w][i] = v[i];
    __syncthreads();
    if (threadIdx.x < 27) {
        float acc = red[0][threadIdx.x] + red[1][threadIdx.x] + red[2][threadIdx.x] + red[3][threadIdx.x];
        int slot = blockIdx.x & 63;
        atomicAdd(&sums1p[(slot * BATCH + b) * 27 + threadIdx.x], acc);
    }
}

// ---------------------------------------------------------------------------
// K3: finalize GN1 stats -> folded per-channel weights w1f[b][c][8]:
// slots 0..5 = s*W1[c][:], slot 6 = t, slot 7 = 0.  1 block x 128 threads.
// ---------------------------------------------------------------------------
__global__ void finalize1_kernel(const float* __restrict__ sums1p,
                                 const float* __restrict__ w1, const float* __restrict__ b1,
                                 const float* __restrict__ g1, const float* __restrict__ beta1,
                                 float* __restrict__ w1f)
{
    __shared__ float S[BATCH][27];
    const int t = threadIdx.x;
    if (t < 108) {
        int b = t / 27, i = t % 27;
        float acc = 0.f;
        for (int s = 0; s < 64; ++s) acc += sums1p[(s * BATCH + b) * 27 + i];
        S[b][i] = acc;
    }
    __syncthreads();
    const int b = t >> 5, c = t & 31;
    const float invS = 1.0f / (float)NKTOT;
    float Ex[6], M[6][6];
#pragma unroll
    for (int d = 0; d < 6; ++d) Ex[d] = S[b][d] * invS;
    int p = 6;
#pragma unroll
    for (int d = 0; d < 6; ++d)
#pragma unroll
        for (int e = d; e < 6; ++e) { float v = S[b][p++] * invS; M[d][e] = v; M[e][d] = v; }
    const int g = c >> 2;
    float msum = 0.f, qsum = 0.f;
    for (int cc = g * 4; cc < g * 4 + 4; ++cc) {
        float w[6];
#pragma unroll
        for (int d = 0; d < 6; ++d) w[d] = w1[cc * 6 + d];
        float dotEx = 0.f;
#pragma unroll
        for (int d = 0; d < 6; ++d) dotEx += w[d] * Ex[d];
        float Ey = dotEx + b1[cc];
        float Ey2 = 0.f;
#pragma unroll
        for (int d = 0; d < 6; ++d)
#pragma unroll
            for (int e = 0; e < 6; ++e) Ey2 += w[d] * w[e] * M[d][e];
        Ey2 += 2.0f * b1[cc] * dotEx + b1[cc] * b1[cc];
        msum += Ey; qsum += Ey2;
    }
    float m = msum * 0.25f;
    float var = qsum * 0.25f - m * m;
    float inv = rsqrtf(var + EPS);
    float s = g1[c] * inv;
    float tt = s * (b1[c] - m) + beta1[c];
    float* o = w1f + (b * 32 + c) * 8;
#pragma unroll
    for (int d = 0; d < 6; ++d) o[d] = s * w1[c * 6 + d];
    o[6] = tt; o[7] = 0.f;
}

// ---------------------------------------------------------------------------
// K4: fused main pass (coalesced idx via [b][k][n]).
// Block = (b, k, 512 n's) as 4 phases of 128 n. z1[32][128] in LDS,
// GEMM thread tile 4c x 8n, running stats in registers, one butterfly +
// 144 atomics per block. grid: 4*20*16 = 1280 blocks x 256 thr.
// ---------------------------------------------------------------------------
__global__ __launch_bounds__(256, 5) void fused_main_kernel(
    const float4* __restrict__ pts4, const int* __restrict__ idxb,
    const float* __restrict__ w1f, const float* __restrict__ w2, const float* __restrict__ b2,
    float* __restrict__ sums2p, unsigned int* __restrict__ maxenc, unsigned int* __restrict__ minenc)
{
    __shared__ __align__(16) float w2t[32 * 64];    // W2^T: [k][c]   8 KB
    __shared__ __align__(16) float z1s[32 * 128];   // z1:   [k][n]  16 KB
    __shared__ __align__(16) float4 w1s4[64];       // folded W1 [32][8]
    __shared__ float b2s[64];
    __shared__ float redmx[256], redmn[256], sqred[128];

    const int t   = threadIdx.x;
    const int blk = blockIdx.x;
    const int nc  = blk & 15;
    const int k   = (blk >> 4) % 20;
    const int b   = blk / 320;          // 320 blocks per batch (16 nc * 20 k)

    for (int i = t; i < 512; i += 256) {
        float4 v = ((const float4*)w2)[i];
        int c = i >> 3, kq = (i & 7) * 4;
        w2t[(kq + 0) * 64 + c] = v.x; w2t[(kq + 1) * 64 + c] = v.y;
        w2t[(kq + 2) * 64 + c] = v.z; w2t[(kq + 3) * 64 + c] = v.w;
    }
    if (t < 64) { w1s4[t] = ((const float4*)w1f)[b * 64 + t]; b2s[t] = b2[t]; }

    const int wvi  = t >> 6;
    const int nf   = t & 127;
    const int cgf  = t >> 7;
    const int cq   = t & 15;
    const int ng   = t >> 4;
    const int c0   = cq * 4;
    const int n0   = ng * 8;
    const float4* pb = pts4 + b * NPTS;
    const int nbase = nc * 512;
    const int* idxrow = idxb + (b * KNN + k) * NPTS;   // [b][k][n]: coalesced

    float mx[4], mn[4];
#pragma unroll
    for (int ci = 0; ci < 4; ++ci) { mx[ci] = -INFINITY; mn[ci] = INFINITY; }
    float gs = 0.f, gq = 0.f;

    for (int ph = 0; ph < 4; ++ph) {
        const int n = nbase + ph * 128 + nf;
        const int j = idxrow[n];
        float4 c4 = pb[n];
        float4 e4 = pb[j];
        float x0[6] = { c4.x, c4.y, c4.z, e4.x - c4.x, e4.y - c4.y, e4.z - c4.z };

        __syncthreads();
#pragma unroll
        for (int jj = 0; jj < 16; ++jj) {
            int c = cgf * 16 + jj;
            float4 wA = w1s4[c * 2 + 0];
            float4 wB = w1s4[c * 2 + 1];
            float z = wB.z;
            z = fmaf(wA.x, x0[0], z); z = fmaf(wA.y, x0[1], z); z = fmaf(wA.z, x0[2], z);
            z = fmaf(wA.w, x0[3], z); z = fmaf(wB.x, x0[4], z); z = fmaf(wB.y, x0[5], z);
            z1s[c * 128 + nf] = eluf(z);
        }
        __syncthreads();

        float acc[4][8];
#pragma unroll
        for (int ci = 0; ci < 4; ++ci) {
            float bb = b2s[c0 + ci];
#pragma unroll
            for (int pj = 0; pj < 8; ++pj) acc[ci][pj] = bb;
        }
#pragma unroll
        for (int kk = 0; kk < 32; ++kk) {
            float4 av = *(const float4*)&w2t[kk * 64 + c0];
            float4 z0 = *(const float4*)&z1s[kk * 128 + n0];
            float4 z1v = *(const float4*)&z1s[kk * 128 + n0 + 4];
            float avv[4] = { av.x, av.y, av.z, av.w };
            float zvv[8] = { z0.x, z0.y, z0.z, z0.w, z1v.x, z1v.y, z1v.z, z1v.w };
#pragma unroll
            for (int ci = 0; ci < 4; ++ci)
#pragma unroll
                for (int pj = 0; pj < 8; ++pj) acc[ci][pj] = fmaf(avv[ci], zvv[pj], acc[ci][pj]);
        }
#pragma unroll
        for (int ci = 0; ci < 4; ++ci)
#pragma unroll
            for (int pj = 0; pj < 8; ++pj) {
                float v = acc[ci][pj];
                gs += v; gq = fmaf(v, v, gq);
                mx[ci] = fmaxf(mx[ci], v); mn[ci] = fminf(mn[ci], v);
            }
    }

#pragma unroll
    for (int m = 16; m <= 32; m <<= 1) {
#pragma unroll
        for (int ci = 0; ci < 4; ++ci) {
            mx[ci] = fmaxf(mx[ci], __shfl_xor(mx[ci], m));
            mn[ci] = fminf(mn[ci], __shfl_xor(mn[ci], m));
        }
        gs += __shfl_xor(gs, m);
        gq += __shfl_xor(gq, m);
    }
    if ((t & 63) < 16) {
#pragma unroll
        for (int ci = 0; ci < 4; ++ci) {
            redmx[wvi * 64 + cq * 4 + ci] = mx[ci];
            redmn[wvi * 64 + cq * 4 + ci] = mn[ci];
        }
        sqred[(wvi * 16 + cq) * 2 + 0] = gs;
        sqred[(wvi * 16 + cq) * 2 + 1] = gq;
    }
    __syncthreads();
    if (t < 64) {
        float m = fmaxf(fmaxf(redmx[t], redmx[64 + t]), fmaxf(redmx[128 + t], redmx[192 + t]));
        atomicMax(&maxenc[(b * 64 + t) * KNN + k], fenc(m));
    } else if (t < 128) {
        int c = t - 64;
        float m = fminf(fminf(redmn[c], redmn[64 + c]), fminf(redmn[128 + c], redmn[192 + c]));
        atomicMin(&minenc[(b * 64 + c) * KNN + k], fenc(m));
    } else if (t < 144) {
        int i2 = t - 128, g = i2 >> 1, w = i2 & 1;
        float v = 0.f;
#pragma unroll
        for (int wv2 = 0; wv2 < 4; ++wv2)
            v += sqred[(wv2 * 16 + 2 * g) * 2 + w] + sqred[(wv2 * 16 + 2 * g + 1) * 2 + w];
        int slot = blk & 63;
        atomicAdd(&sums2p[((slot * BATCH + b) * 8 + g) * 2 + w], v);
    }
}

// ---------------------------------------------------------------------------
// K5: build m1[b,c,k] = ELU(GN2-affine applied to max-or-min over n of y2)
// ---------------------------------------------------------------------------
__global__ void build_m1_kernel(const float* __restrict__ sums2p,
                                const unsigned int* __restrict__ maxenc,
                                const unsigned int* __restrict__ minenc,
                                const float* __restrict__ gamma, const float* __restrict__ beta,
                                float* __restrict__ m1)
{
    const int t = blockIdx.x * 256 + threadIdx.x;   // (b*64+c)*20+k
    const int b = t / 1280;
    const int r = t - b * 1280;
    const int c = r / 20;
    const int g = c >> 3;
    float s = 0.f, q = 0.f;
    for (int sl = 0; sl < 64; ++sl) {
        s += sums2p[((sl * BATCH + b) * 8 + g) * 2 + 0];
        q += sums2p[((sl * BATCH + b) * 8 + g) * 2 + 1];
    }
    const float cnt = 8.0f * (float)NKTOT;
    float m = s / cnt;
    float var = q / cnt - m * m;
    float inv = rsqrtf(var + EPS);
    float sc = gamma[c] * inv;
    float tt = beta[c] - sc * m;
    float y = (sc >= 0.f) ? fdec(maxenc[t]) : fdec(minenc[t]);
    m1[t] = elu(sc * y + tt);
}

// ---------------------------------------------------------------------------
// K6/K8: pointwise conv (CIN -> COUT over K=20) + raw output + GN stat partials
// ---------------------------------------------------------------------------
template <int CIN, int SLOTS>
__global__ void p2_gemm_kernel(const float* __restrict__ zin, const float* __restrict__ w,
                               const float* __restrict__ bias, float* __restrict__ yout,
                               float* __restrict__ sumsp, int chans_per_group)
{
    const int t = blockIdx.x * 256 + threadIdx.x;
    const int per_b = (gridDim.x * 256) / BATCH;
    const int b = t / per_b;
    const int r = t - b * per_b;
    const int o = r / 20;
    const int k = r - o * 20;
    const float* zb = zin + b * CIN * 20;
    const float* wrow = w + o * CIN;
    float acc = bias[o];
    for (int c = 0; c < CIN; c += 4) {
        float4 wv = *(const float4*)&wrow[c];
        acc += wv.x * zb[(c + 0) * 20 + k] + wv.y * zb[(c + 1) * 20 + k]
             + wv.z * zb[(c + 2) * 20 + k] + wv.w * zb[(c + 3) * 20 + k];
    }
    yout[t] = acc;

    __shared__ float ls[16];
    if (threadIdx.x < 16) ls[threadIdx.x] = 0.f;
    __syncthreads();
    const int g = o / chans_per_group;
    atomicAdd(&ls[g * 2 + 0], acc);
    atomicAdd(&ls[g * 2 + 1], acc * acc);
    __syncthreads();
    if (threadIdx.x < 16) {
        int slot = blockIdx.x & (SLOTS - 1);
        atomicAdd(&sumsp[(slot * BATCH + b) * 16 + threadIdx.x], ls[threadIdx.x]);
    }
}

// K7/K9: apply GN affine + ELU using partial sums
template <int SLOTS>
__global__ void p2_finalize_kernel(const float* __restrict__ y, const float* __restrict__ sumsp,
                                   const float* __restrict__ gamma, const float* __restrict__ beta,
                                   float* __restrict__ z, int chans_per_group, float cnt)
{
    const int t = blockIdx.x * 256 + threadIdx.x;
    const int per_b = (gridDim.x * 256) / BATCH;
    const int b = t / per_b;
    const int r = t - b * per_b;
    const int o = r / 20;
    const int g = o / chans_per_group;
    float s = 0.f, q = 0.f;
    for (int sl = 0; sl < SLOTS; ++sl) {
        s += sumsp[(sl * BATCH + b) * 16 + g * 2 + 0];
        q += sumsp[(sl * BATCH + b) * 16 + g * 2 + 1];
    }
    float m = s / cnt;
    float var = q / cnt - m * m;
    float inv = rsqrtf(var + EPS);
    float v = gamma[o] * inv * (y[t] - m) + beta[o];
    z[t] = elu(v);
}

// ---------------------------------------------------------------------------
extern "C" void kernel_launch(void* const* d_in, const int* in_sizes, int n_in,
                              void* d_out, int out_size, void* d_ws, size_t ws_size,
                              hipStream_t stream)
{
    const float* points  = (const float*)d_in[0];
    const float* p1_w0   = (const float*)d_in[1];
    const float* p1_b0   = (const float*)d_in[2];
    const float* p1_g0   = (const float*)d_in[3];
    const float* p1_bt0  = (const float*)d_in[4];
    const float* p1_w1   = (const float*)d_in[5];
    const float* p1_b1   = (const float*)d_in[6];
    const float* p1_g1   = (const float*)d_in[7];
    const float* p1_bt1  = (const float*)d_in[8];
    const float* p2_w0   = (const float*)d_in[9];
    const float* p2_b0   = (const float*)d_in[10];
    const float* p2_g0   = (const float*)d_in[11];
    const float* p2_bt0  = (const float*)d_in[12];
    const float* p2_w1   = (const float*)d_in[13];
    const float* p2_b1   = (const float*)d_in[14];
    const float* p2_g1   = (const float*)d_in[15];
    const float* p2_bt1  = (const float*)d_in[16];
    float* out = (float*)d_out;

    float* ws = (float*)d_ws;
    int*      idx     = (int*)ws;                    // 655360  ([b][k][n])
    float*    sums1p  = ws + 655360;                 // 6912   (zero)
    float*    sums2p  = sums1p + 6912;               // 4096   (zero)
    float*    sumsAp  = sums2p + 4096;               // 1024   (zero)
    float*    sumsBp  = sumsAp + 1024;               // 1024   (zero)
    unsigned* maxenc  = (unsigned*)(sumsBp + 1024);  // 5120   (zero)
    unsigned* minenc  = maxenc + 5120;               // 5120   (0xFF)
    float*    w1f     = (float*)(minenc + 5120);     // 1024
    float*    m1      = w1f + 1024;                  // 5120
    float*    yp2a    = m1 + 5120;                   // 40960
    float*    zp2a    = yp2a + 40960;                // 40960
    float*    yp2b    = zp2a + 40960;                // 81920
    // pts4 (32768 float4 = 131072 floats) aliases yp2a onward; live only
    // until fused_main_kernel completes (before yp2a/zp2a/yp2b are written).
    float4*   pts4    = (float4*)yp2a;

    hipMemsetAsync(sums1p, 0, (6912 + 4096 + 1024 + 1024 + 5120) * sizeof(float), stream);
    hipMemsetAsync(minenc, 0xFF, 5120 * sizeof(unsigned), stream);

    prep_kernel<<<128, 256, 0, stream>>>(points, pts4);
    knn_kernel<<<512, 512, 0, stream>>>(pts4, idx);
    moments_x_kernel<<<320, 256, 0, stream>>>(pts4, idx, sums1p);
    finalize1_kernel<<<1, 128, 0, stream>>>(sums1p, p1_w0, p1_b0, p1_g0, p1_bt0, w1f);
    // grid MUST be 1280 = 4 b * 20 k * 16 nc  (b = blk/320; larger grids give
    // b >= BATCH -> OOB idx reads -> memory fault, see R4 crash)
    fused_main_kernel<<<1280, 256, 0, stream>>>(pts4, idx, w1f, p1_w1, p1_b1,
                                                sums2p, maxenc, minenc);
    build_m1_kernel<<<20, 256, 0, stream>>>(sums2p, maxenc, minenc, p1_g1, p1_bt1, m1);
    p2_gemm_kernel<64, 16><<<160, 256, 0, stream>>>(m1, p2_w0, p2_b0, yp2a, sumsAp, 64);
    p2_finalize_kernel<16><<<160, 256, 0, stream>>>(yp2a, sumsAp, p2_g0, p2_bt0, zp2a, 64, 1280.0f);
    p2_gemm_kernel<512, 16><<<320, 256, 0, stream>>>(zp2a, p2_w1, p2_b1, yp2b, sumsBp, 128);
    p2_finalize_kernel<16><<<320, 256, 0, stream>>>(yp2b, sumsBp, p2_g1, p2_bt1, out, 128, 2560.0f);
}

// Round 15
// 264.254 us; speedup vs baseline: 1.3348x; 1.0324x over previous
//
#include <hip/hip_runtime.h>
#include <math.h>

#define NPTS   8192
#define BATCH  4
#define KNN    20
#define NKTOT  (NPTS*KNN)        // 163840 spatial positions per batch
#define EPS    1e-5f
#define QC     28                // per-(wave,query) private queue cap (10-sigma)

typedef float v2f __attribute__((ext_vector_type(2)));

__device__ __forceinline__ float elu(float x) { return x > 0.0f ? x : expm1f(x); }
__device__ __forceinline__ float eluf(float x) { return x > 0.0f ? x : __expf(x) - 1.0f; }
__device__ __forceinline__ v2f splat2(float x) { v2f v; v.x = x; v.y = x; return v; }
__device__ __forceinline__ float rfl(float x) {
    return __uint_as_float(__builtin_amdgcn_readfirstlane(__float_as_uint(x)));
}

// monotone float <-> unsigned encoding for atomic max/min on floats
__device__ __forceinline__ unsigned fenc(float f) {
    unsigned b = __float_as_uint(f);
    return b ^ ((unsigned)(((int)b) >> 31) | 0x80000000u);
}
__device__ __forceinline__ float fdec(unsigned u) {
    unsigned b = (u & 0x80000000u) ? (u ^ 0x80000000u) : ~u;
    return __uint_as_float(b);
}

// ---------------------------------------------------------------------------
// K0: pack points into (x,y,z,-0.5*|p|^2) so knn score s = q.p + w gives
// dist = |q|^2 - 2s (ordering by s is exactly ordering by dist).
// ---------------------------------------------------------------------------
__global__ __launch_bounds__(256) void prep_kernel(const float* __restrict__ points,
                                                   float4* __restrict__ pts4)
{
    const int t = blockIdx.x * 256 + threadIdx.x;     // 32768
    const int b = t >> 13, n = t & (NPTS - 1);
    const float* px = points + b * 3 * NPTS;
    float x = px[n], y = px[NPTS + n], z = px[2 * NPTS + n];
    pts4[t] = make_float4(x, y, z, -0.5f * (x * x + y * y + z * z));
}

// ---------------------------------------------------------------------------
// K1: exact KNN, candidate-split v2 (fixes R12's two overheads):
// 2 waves per query-octet, each streams HALF the candidates from L2.
// (a) gate sorts are SPLIT not duplicated: per-octet lane-maxima halves
//     are combined elementwise in LDS (== R9's full-scan lane-max vector,
//     since halves partition each lane's 128 candidates) and each wave
//     sorts only 4 queries; gate = rank-44 - margin (same proof as R9).
// (b) queues are WAVE-PRIVATE (no cross-wave atomic contention); final
//     sort concatenates the two private queues (<=56 of 64 lanes) —
//     bitonic + tie-packed keys give exact lax.top_k order regardless.
// idx_out layout [b][k][n]. grid: 2048 blocks x 256 thr (8 waves/SIMD).
// ---------------------------------------------------------------------------
__global__ __launch_bounds__(256, 8) void knn_kernel(const float4* __restrict__ pts4,
                                                     int* __restrict__ idx_out)
{
    __shared__ unsigned long long queue[32][QC];   // 7 KB  (4 waves x 8 q)
    __shared__ float smaxs[4][8][64];              // 8 KB  lane maxima halves
    __shared__ float gates[2][8];
    __shared__ int qcnt[32];

    const int tid  = threadIdx.x;
    const int lane = tid & 63;
    const int wv   = tid >> 6;            // 0..3
    const int oct  = wv >> 1;             // octet in block 0/1
    const int par  = wv & 1;              // candidate half 0/1
    const int b    = blockIdx.x >> 9;     // 512 blocks per batch
    const int q0   = (blockIdx.x & 511) * 16 + oct * 8;
    const float4* pb = pts4 + b * NPTS;
    const int cbase = par * (NPTS / 2);

    if (tid < 32) qcnt[tid] = 0;

    float qx[8], qy[8], qz[8];
    v2f smax2[8];
#pragma unroll
    for (int q = 0; q < 8; ++q) {
        float4 qp = pb[q0 + q];
        qx[q] = rfl(qp.x); qy[q] = rfl(qp.y); qz[q] = rfl(qp.z);
        smax2[q] = splat2(-INFINITY);
    }

    // ---- pass 1: per-lane max over this wave's half (32 iters x 128) ----
#pragma unroll 4
    for (int t = 0; t < NPTS / 2 / 128; ++t) {
        float4 p0 = pb[cbase + t * 128 + 2 * lane];
        float4 p1 = pb[cbase + t * 128 + 2 * lane + 1];
        v2f px = { p0.x, p1.x }, py = { p0.y, p1.y };
        v2f pz = { p0.z, p1.z }, pw = { p0.w, p1.w };
#pragma unroll
        for (int q = 0; q < 8; ++q) {
            v2f sv = __builtin_elementwise_fma(splat2(qx[q]), px,
                     __builtin_elementwise_fma(splat2(qy[q]), py,
                     __builtin_elementwise_fma(splat2(qz[q]), pz, pw)));
            smax2[q] = __builtin_elementwise_max(smax2[q], sv);
        }
    }
#pragma unroll
    for (int q = 0; q < 8; ++q) smaxs[wv][q][lane] = fmaxf(smax2[q].x, smax2[q].y);
    __syncthreads();

    // ---- gate: combine halves elementwise (== full-scan lane maxima),
    //      each wave sorts 4 queries; rank-44 = LB on global 20th-best ----
#pragma unroll
    for (int qq = 0; qq < 4; ++qq) {
        const int q = par * 4 + qq;
        float v = fmaxf(smaxs[2 * oct][q][lane], smaxs[2 * oct + 1][q][lane]);
#pragma unroll
        for (int k = 2; k <= 64; k <<= 1)
#pragma unroll
            for (int j = k >> 1; j >= 1; j >>= 1) {
                float o = __shfl_xor(v, j);
                bool up = ((lane & k) == 0);
                bool keepmin = (((lane & j) == 0) == up);
                v = keepmin ? fminf(v, o) : fmaxf(v, o);
            }
        float m = __shfl(v, 44);
        if (lane == 0) gates[oct][q] = m - 1e-4f - 1e-5f * fabsf(m);
    }
    __syncthreads();
    float sgate[8];
#pragma unroll
    for (int q = 0; q < 8; ++q) sgate[q] = gates[oct][q];

    // ---- pass 2: gated append into WAVE-PRIVATE queues ----
    for (int t = 0; t < NPTS / 2 / 128; ++t) {
        float4 p0 = pb[cbase + t * 128 + 2 * lane];
        float4 p1 = pb[cbase + t * 128 + 2 * lane + 1];
        v2f px = { p0.x, p1.x }, py = { p0.y, p1.y };
        v2f pz = { p0.z, p1.z }, pw = { p0.w, p1.w };
        const int jb = cbase + t * 128 + 2 * lane;
#pragma unroll
        for (int q = 0; q < 8; ++q) {
            v2f sv = __builtin_elementwise_fma(splat2(qx[q]), px,
                     __builtin_elementwise_fma(splat2(qy[q]), py,
                     __builtin_elementwise_fma(splat2(qz[q]), pz, pw)));
            if (fmaxf(sv.x, sv.y) >= sgate[q]) {     // common case: whole wave skips
#pragma unroll
                for (int h = 0; h < 2; ++h) {
                    float svh = h ? sv.y : sv.x;
                    if (svh >= sgate[q]) {
                        int slot = atomicAdd(&qcnt[wv * 8 + q], 1);
                        if (slot < QC) {
                            unsigned long long key =
                                ((unsigned long long)fenc(svh) << 32)
                                | (unsigned)(NPTS - 1 - (jb + h));
                            queue[wv * 8 + q][slot] = key;
                        }
                    }
                }
            }
        }
    }
    __syncthreads();

    // ---- final: concatenate the octet's two private queues, sort, emit ----
#pragma unroll
    for (int qq = 0; qq < 4; ++qq) {
        const int q = par * 4 + qq;
        int cA = qcnt[(2 * oct) * 8 + q];     cA = cA < QC ? cA : QC;
        int cB = qcnt[(2 * oct + 1) * 8 + q]; cB = cB < QC ? cB : QC;
        unsigned long long key = 0ull;
        if (lane < cA)           key = queue[(2 * oct) * 8 + q][lane];
        else if (lane < cA + cB) key = queue[(2 * oct + 1) * 8 + q][lane - cA];
#pragma unroll
        for (int k = 2; k <= 64; k <<= 1)
#pragma unroll
            for (int j = k >> 1; j >= 1; j >>= 1) {
                unsigned long long o = __shfl_xor(key, j);
                bool up = ((lane & k) == 0);
                bool keepmax = (((lane & j) == 0) == up);
                bool omax = o > key;
                key = (keepmax == omax) ? o : key;
            }
        if (lane < KNN)
            idx_out[(b * KNN + lane) * NPTS + (q0 + q)] =     // [b][k][n]
                NPTS - 1 - (int)(unsigned)(key & 0xFFFFFFFFu);
    }
}

// ---------------------------------------------------------------------------
// K2: x0 moments (6 sums + 21 upper-tri products). Each thread accumulates
// 8 elements; neighbor gather is ONE cache line via pts4[j].
// grid: 320 blocks x 256 threads (80 blocks/batch, 2048 elems/block).
// ---------------------------------------------------------------------------
__global__ __launch_bounds__(256) void moments_x_kernel(const float4* __restrict__ pts4,
                                                        const int* __restrict__ idx,
                                                        float* __restrict__ sums1p)
{
    const int b  = blockIdx.x / 80;
    const int r0 = (blockIdx.x - b * 80) * 2048;
    const float4* pb = pts4 + b * NPTS;
    const int* ib = idx + b * NKTOT;

    float v[27];
#pragma unroll
    for (int i = 0; i < 27; ++i) v[i] = 0.f;

    for (int e = 0; e < 8; ++e) {
        const int id = r0 + e * 256 + threadIdx.x;   // [k][n] linear, coalesced
        const int n = id & (NPTS - 1);
        const int j = ib[id];
        float4 c4 = pb[n];
        float4 e4 = pb[j];
        float x[6] = { c4.x, c4.y, c4.z, e4.x - c4.x, e4.y - c4.y, e4.z - c4.z };
        int p = 6;
#pragma unroll
        for (int d = 0; d < 6; ++d) {
            v[d] += x[d];
#pragma unroll
            for (int ee = d; ee < 6; ++ee) v[p++] += x[d] * x[ee];
        }
    }
#pragma unroll
    for (int i = 0; i < 27; ++i)
        for (int o = 32; o > 0; o >>= 1) v[i] += __shfl_xor(v[i], o);

    __shared__ float red[4][27];
    const int lane = threadIdx.x & 63, w = threadIdx.x >> 6;
    if (lane == 0)
#pragma unroll
        for (int i = 0; i < 27; ++i) red[w][i] = v[i];
    __syncthreads();
    if (threadIdx.x < 27) {
        float acc = red[0][threadIdx.x] + red[1][threadIdx.x] + red[2][threadIdx.x] + red[3][threadIdx.x];
        int slot = blockIdx.x & 63;
        atomicAdd(&sums1p[(slot * BATCH + b) * 27 + threadIdx.x], acc);
    }
}

// ---------------------------------------------------------------------------
// K3: finalize GN1 stats -> folded per-channel weights w1f[b][c][8]:
// slots 0..5 = s*W1[c][:], slot 6 = t, slot 7 = 0.  1 block x 128 threads.
// ---------------------------------------------------------------------------
__global__ void finalize1_kernel(const float* __restrict__ sums1p,
                                 const float* __restrict__ w1, const float* __restrict__ b1,
                                 const float* __restrict__ g1, const float* __restrict__ beta1,
                                 float* __restrict__ w1f)
{
    __shared__ float S[BATCH][27];
    const int t = threadIdx.x;
    if (t < 108) {
        int b = t / 27, i = t % 27;
        float acc = 0.f;
        for (int s = 0; s < 64; ++s) acc += sums1p[(s * BATCH + b) * 27 + i];
        S[b][i] = acc;
    }
    __syncthreads();
    const int b = t >> 5, c = t & 31;
    const float invS = 1.0f / (float)NKTOT;
    float Ex[6], M[6][6];
#pragma unroll
    for (int d = 0; d < 6; ++d) Ex[d] = S[b][d] * invS;
    int p = 6;
#pragma unroll
    for (int d = 0; d < 6; ++d)
#pragma unroll
        for (int e = d; e < 6; ++e) { float v = S[b][p++] * invS; M[d][e] = v; M[e][d] = v; }
    const int g = c >> 2;
    float msum = 0.f, qsum = 0.f;
    for (int cc = g * 4; cc < g * 4 + 4; ++cc) {
        float w[6];
#pragma unroll
        for (int d = 0; d < 6; ++d) w[d] = w1[cc * 6 + d];
        float dotEx = 0.f;
#pragma unroll
        for (int d = 0; d < 6; ++d) dotEx += w[d] * Ex[d];
        float Ey = dotEx + b1[cc];
        float Ey2 = 0.f;
#pragma unroll
        for (int d = 0; d < 6; ++d)
#pragma unroll
            for (int e = 0; e < 6; ++e) Ey2 += w[d] * w[e] * M[d][e];
        Ey2 += 2.0f * b1[cc] * dotEx + b1[cc] * b1[cc];
        msum += Ey; qsum += Ey2;
    }
    float m = msum * 0.25f;
    float var = qsum * 0.25f - m * m;
    float inv = rsqrtf(var + EPS);
    float s = g1[c] * inv;
    float tt = s * (b1[c] - m) + beta1[c];
    float* o = w1f + (b * 32 + c) * 8;
#pragma unroll
    for (int d = 0; d < 6; ++d) o[d] = s * w1[c * 6 + d];
    o[6] = tt; o[7] = 0.f;
}

// ---------------------------------------------------------------------------
// K4: fused main pass (coalesced idx via [b][k][n]).
// Block = (b, k, 512 n's) as 4 phases of 128 n. z1[32][128] in LDS,
// GEMM thread tile 4c x 8n, running stats in registers, one butterfly +
// 144 atomics per block. grid: 4*20*16 = 1280 blocks x 256 thr.
// ---------------------------------------------------------------------------
__global__ __launch_bounds__(256, 5) void fused_main_kernel(
    const float4* __restrict__ pts4, const int* __restrict__ idxb,
    const float* __restrict__ w1f, const float* __restrict__ w2, const float* __restrict__ b2,
    float* __restrict__ sums2p, unsigned int* __restrict__ maxenc, unsigned int* __restrict__ minenc)
{
    __shared__ __align__(16) float w2t[32 * 64];    // W2^T: [k][c]   8 KB
    __shared__ __align__(16) float z1s[32 * 128];   // z1:   [k][n]  16 KB
    __shared__ __align__(16) float4 w1s4[64];       // folded W1 [32][8]
    __shared__ float b2s[64];
    __shared__ float redmx[256], redmn[256], sqred[128];

    const int t   = threadIdx.x;
    const int blk = blockIdx.x;
    const int nc  = blk & 15;
    const int k   = (blk >> 4) % 20;
    const int b   = blk / 320;          // 320 blocks per batch (16 nc * 20 k)

    for (int i = t; i < 512; i += 256) {
        float4 v = ((const float4*)w2)[i];
        int c = i >> 3, kq = (i & 7) * 4;
        w2t[(kq + 0) * 64 + c] = v.x; w2t[(kq + 1) * 64 + c] = v.y;
        w2t[(kq + 2) * 64 + c] = v.z; w2t[(kq + 3) * 64 + c] = v.w;
    }
    if (t < 64) { w1s4[t] = ((const float4*)w1f)[b * 64 + t]; b2s[t] = b2[t]; }

    const int wvi  = t >> 6;
    const int nf   = t & 127;
    const int cgf  = t >> 7;
    const int cq   = t & 15;
    const int ng   = t >> 4;
    const int c0   = cq * 4;
    const int n0   = ng * 8;
    const float4* pb = pts4 + b * NPTS;
    const int nbase = nc * 512;
    const int* idxrow = idxb + (b * KNN + k) * NPTS;   // [b][k][n]: coalesced

    float mx[4], mn[4];
#pragma unroll
    for (int ci = 0; ci < 4; ++ci) { mx[ci] = -INFINITY; mn[ci] = INFINITY; }
    float gs = 0.f, gq = 0.f;

    for (int ph = 0; ph < 4; ++ph) {
        const int n = nbase + ph * 128 + nf;
        const int j = idxrow[n];
        float4 c4 = pb[n];
        float4 e4 = pb[j];
        float x0[6] = { c4.x, c4.y, c4.z, e4.x - c4.x, e4.y - c4.y, e4.z - c4.z };

        __syncthreads();
#pragma unroll
        for (int jj = 0; jj < 16; ++jj) {
            int c = cgf * 16 + jj;
            float4 wA = w1s4[c * 2 + 0];
            float4 wB = w1s4[c * 2 + 1];
            float z = wB.z;
            z = fmaf(wA.x, x0[0], z); z = fmaf(wA.y, x0[1], z); z = fmaf(wA.z, x0[2], z);
            z = fmaf(wA.w, x0[3], z); z = fmaf(wB.x, x0[4], z); z = fmaf(wB.y, x0[5], z);
            z1s[c * 128 + nf] = eluf(z);
        }
        __syncthreads();

        float acc[4][8];
#pragma unroll
        for (int ci = 0; ci < 4; ++ci) {
            float bb = b2s[c0 + ci];
#pragma unroll
            for (int pj = 0; pj < 8; ++pj) acc[ci][pj] = bb;
        }
#pragma unroll
        for (int kk = 0; kk < 32; ++kk) {
            float4 av = *(const float4*)&w2t[kk * 64 + c0];
            float4 z0 = *(const float4*)&z1s[kk * 128 + n0];
            float4 z1v = *(const float4*)&z1s[kk * 128 + n0 + 4];
            float avv[4] = { av.x, av.y, av.z, av.w };
            float zvv[8] = { z0.x, z0.y, z0.z, z0.w, z1v.x, z1v.y, z1v.z, z1v.w };
#pragma unroll
            for (int ci = 0; ci < 4; ++ci)
#pragma unroll
                for (int pj = 0; pj < 8; ++pj) acc[ci][pj] = fmaf(avv[ci], zvv[pj], acc[ci][pj]);
        }
#pragma unroll
        for (int ci = 0; ci < 4; ++ci)
#pragma unroll
            for (int pj = 0; pj < 8; ++pj) {
                float v = acc[ci][pj];
                gs += v; gq = fmaf(v, v, gq);
                mx[ci] = fmaxf(mx[ci], v); mn[ci] = fminf(mn[ci], v);
            }
    }

#pragma unroll
    for (int m = 16; m <= 32; m <<= 1) {
#pragma unroll
        for (int ci = 0; ci < 4; ++ci) {
            mx[ci] = fmaxf(mx[ci], __shfl_xor(mx[ci], m));
            mn[ci] = fminf(mn[ci], __shfl_xor(mn[ci], m));
        }
        gs += __shfl_xor(gs, m);
        gq += __shfl_xor(gq, m);
    }
    if ((t & 63) < 16) {
#pragma unroll
        for (int ci = 0; ci < 4; ++ci) {
            redmx[wvi * 64 + cq * 4 + ci] = mx[ci];
            redmn[wvi * 64 + cq * 4 + ci] = mn[ci];
        }
        sqred[(wvi * 16 + cq) * 2 + 0] = gs;
        sqred[(wvi * 16 + cq) * 2 + 1] = gq;
    }
    __syncthreads();
    if (t < 64) {
        float m = fmaxf(fmaxf(redmx[t], redmx[64 + t]), fmaxf(redmx[128 + t], redmx[192 + t]));
        atomicMax(&maxenc[(b * 64 + t) * KNN + k], fenc(m));
    } else if (t < 128) {
        int c = t - 64;
        float m = fminf(fminf(redmn[c], redmn[64 + c]), fminf(redmn[128 + c], redmn[192 + c]));
        atomicMin(&minenc[(b * 64 + c) * KNN + k], fenc(m));
    } else if (t < 144) {
        int i2 = t - 128, g = i2 >> 1, w = i2 & 1;
        float v = 0.f;
#pragma unroll
        for (int wv2 = 0; wv2 < 4; ++wv2)
            v += sqred[(wv2 * 16 + 2 * g) * 2 + w] + sqred[(wv2 * 16 + 2 * g + 1) * 2 + w];
        int slot = blk & 63;
        atomicAdd(&sums2p[((slot * BATCH + b) * 8 + g) * 2 + w], v);
    }
}

// ---------------------------------------------------------------------------
// K5: build m1[b,c,k] = ELU(GN2-affine applied to max-or-min over n of y2)
// ---------------------------------------------------------------------------
__global__ void build_m1_kernel(const float* __restrict__ sums2p,
                                const unsigned int* __restrict__ maxenc,
                                const unsigned int* __restrict__ minenc,
                                const float* __restrict__ gamma, const float* __restrict__ beta,
                                float* __restrict__ m1)
{
    const int t = blockIdx.x * 256 + threadIdx.x;   // (b*64+c)*20+k
    const int b = t / 1280;
    const int r = t - b * 1280;
    const int c = r / 20;
    const int g = c >> 3;
    float s = 0.f, q = 0.f;
    for (int sl = 0; sl < 64; ++sl) {
        s += sums2p[((sl * BATCH + b) * 8 + g) * 2 + 0];
        q += sums2p[((sl * BATCH + b) * 8 + g) * 2 + 1];
    }
    const float cnt = 8.0f * (float)NKTOT;
    float m = s / cnt;
    float var = q / cnt - m * m;
    float inv = rsqrtf(var + EPS);
    float sc = gamma[c] * inv;
    float tt = beta[c] - sc * m;
    float y = (sc >= 0.f) ? fdec(maxenc[t]) : fdec(minenc[t]);
    m1[t] = elu(sc * y + tt);
}

// ---------------------------------------------------------------------------
// K6/K8: pointwise conv (CIN -> COUT over K=20) + raw output + GN stat partials
// ---------------------------------------------------------------------------
template <int CIN, int SLOTS>
__global__ void p2_gemm_kernel(const float* __restrict__ zin, const float* __restrict__ w,
                               const float* __restrict__ bias, float* __restrict__ yout,
                               float* __restrict__ sumsp, int chans_per_group)
{
    const int t = blockIdx.x * 256 + threadIdx.x;
    const int per_b = (gridDim.x * 256) / BATCH;
    const int b = t / per_b;
    const int r = t - b * per_b;
    const int o = r / 20;
    const int k = r - o * 20;
    const float* zb = zin + b * CIN * 20;
    const float* wrow = w + o * CIN;
    float acc = bias[o];
    for (int c = 0; c < CIN; c += 4) {
        float4 wv = *(const float4*)&wrow[c];
        acc += wv.x * zb[(c + 0) * 20 + k] + wv.y * zb[(c + 1) * 20 + k]
             + wv.z * zb[(c + 2) * 20 + k] + wv.w * zb[(c + 3) * 20 + k];
    }
    yout[t] = acc;

    __shared__ float ls[16];
    if (threadIdx.x < 16) ls[threadIdx.x] = 0.f;
    __syncthreads();
    const int g = o / chans_per_group;
    atomicAdd(&ls[g * 2 + 0], acc);
    atomicAdd(&ls[g * 2 + 1], acc * acc);
    __syncthreads();
    if (threadIdx.x < 16) {
        int slot = blockIdx.x & (SLOTS - 1);
        atomicAdd(&sumsp[(slot * BATCH + b) * 16 + threadIdx.x], ls[threadIdx.x]);
    }
}

// K7/K9: apply GN affine + ELU using partial sums
template <int SLOTS>
__global__ void p2_finalize_kernel(const float* __restrict__ y, const float* __restrict__ sumsp,
                                   const float* __restrict__ gamma, const float* __restrict__ beta,
                                   float* __restrict__ z, int chans_per_group, float cnt)
{
    const int t = blockIdx.x * 256 + threadIdx.x;
    const int per_b = (gridDim.x * 256) / BATCH;
    const int b = t / per_b;
    const int r = t - b * per_b;
    const int o = r / 20;
    const int g = o / chans_per_group;
    float s = 0.f, q = 0.f;
    for (int sl = 0; sl < SLOTS; ++sl) {
        s += sumsp[(sl * BATCH + b) * 16 + g * 2 + 0];
        q += sumsp[(sl * BATCH + b) * 16 + g * 2 + 1];
    }
    float m = s / cnt;
    float var = q / cnt - m * m;
    float inv = rsqrtf(var + EPS);
    float v = gamma[o] * inv * (y[t] - m) + beta[o];
    z[t] = elu(v);
}

// ---------------------------------------------------------------------------
extern "C" void kernel_launch(void* const* d_in, const int* in_sizes, int n_in,
                              void* d_out, int out_size, void* d_ws, size_t ws_size,
                              hipStream_t stream)
{
    const float* points  = (const float*)d_in[0];
    const float* p1_w0   = (const float*)d_in[1];
    const float* p1_b0   = (const float*)d_in[2];
    const float* p1_g0   = (const float*)d_in[3];
    const float* p1_bt0  = (const float*)d_in[4];
    const float* p1_w1   = (const float*)d_in[5];
    const float* p1_b1   = (const float*)d_in[6];
    const float* p1_g1   = (const float*)d_in[7];
    const float* p1_bt1  = (const float*)d_in[8];
    const float* p2_w0   = (const float*)d_in[9];
    const float* p2_b0   = (const float*)d_in[10];
    const float* p2_g0   = (const float*)d_in[11];
    const float* p2_bt0  = (const float*)d_in[12];
    const float* p2_w1   = (const float*)d_in[13];
    const float* p2_b1   = (const float*)d_in[14];
    const float* p2_g1   = (const float*)d_in[15];
    const float* p2_bt1  = (const float*)d_in[16];
    float* out = (float*)d_out;

    float* ws = (float*)d_ws;
    int*      idx     = (int*)ws;                    // 655360  ([b][k][n])
    float*    sums1p  = ws + 655360;                 // 6912   (zero)
    float*    sums2p  = sums1p + 6912;               // 4096   (zero)
    float*    sumsAp  = sums2p + 4096;               // 1024   (zero)
    float*    sumsBp  = sumsAp + 1024;               // 1024   (zero)
    unsigned* maxenc  = (unsigned*)(sumsBp + 1024);  // 5120   (zero)
    unsigned* minenc  = maxenc + 5120;               // 5120   (0xFF)
    float*    w1f     = (float*)(minenc + 5120);     // 1024
    float*    m1      = w1f + 1024;                  // 5120
    float*    yp2a    = m1 + 5120;                   // 40960
    float*    zp2a    = yp2a + 40960;                // 40960
    float*    yp2b    = zp2a + 40960;                // 81920
    // pts4 (32768 float4 = 131072 floats) aliases yp2a onward; live only
    // until fused_main_kernel completes (before yp2a/zp2a/yp2b are written).
    float4*   pts4    = (float4*)yp2a;

    hipMemsetAsync(sums1p, 0, (6912 + 4096 + 1024 + 1024 + 5120) * sizeof(float), stream);
    hipMemsetAsync(minenc, 0xFF, 5120 * sizeof(unsigned), stream);

    prep_kernel<<<128, 256, 0, stream>>>(points, pts4);
    knn_kernel<<<2048, 256, 0, stream>>>(pts4, idx);
    moments_x_kernel<<<320, 256, 0, stream>>>(pts4, idx, sums1p);
    finalize1_kernel<<<1, 128, 0, stream>>>(sums1p, p1_w0, p1_b0, p1_g0, p1_bt0, w1f);
    // grid MUST be 1280 = 4 b * 20 k * 16 nc  (b = blk/320; larger grids give
    // b >= BATCH -> OOB idx reads -> memory fault, see R4 crash)
    fused_main_kernel<<<1280, 256, 0, stream>>>(pts4, idx, w1f, p1_w1, p1_b1,
                                                sums2p, maxenc, minenc);
    build_m1_kernel<<<20, 256, 0, stream>>>(sums2p, maxenc, minenc, p1_g1, p1_bt1, m1);
    p2_gemm_kernel<64, 16><<<160, 256, 0, stream>>>(m1, p2_w0, p2_b0, yp2a, sumsAp, 64);
    p2_finalize_kernel<16><<<160, 256, 0, stream>>>(yp2a, sumsAp, p2_g0, p2_bt0, zp2a, 64, 1280.0f);
    p2_gemm_kernel<512, 16><<<320, 256, 0, stream>>>(zp2a, p2_w1, p2_b1, yp2b, sumsBp, 128);
    p2_finalize_kernel<16><<<320, 256, 0, stream>>>(yp2b, sumsBp, p2_g1, p2_bt1, out, 128, 2560.0f);
}